// Round 6
// baseline (476.052 us; speedup 1.0000x reference)
//
#include <hip/hip_runtime.h>

#define B_ 8
#define E_ 32768
#define N_ 4096
#define D_ 64
#define R_ 500
#define L_ 3
#define EPS_ 1e-5f

typedef short bf16x8 __attribute__((ext_vector_type(8)));
typedef float f32x4 __attribute__((ext_vector_type(4)));

__device__ __forceinline__ float sigm(float x){ return 1.0f/(1.0f+__expf(-x)); }
__device__ __forceinline__ unsigned short f2bf(float x){
  unsigned u = __float_as_uint(x);
  u += 0x7fffu + ((u>>16)&1u);
  return (unsigned short)(u>>16);
}
__device__ __forceinline__ bf16x8 pk8(float4 a0, float4 a1, float4 b0, float4 b1){
  bf16x8 v;
  v[0]=(short)f2bf(a0.x*b0.x); v[1]=(short)f2bf(a0.y*b0.y);
  v[2]=(short)f2bf(a0.z*b0.z); v[3]=(short)f2bf(a0.w*b0.w);
  v[4]=(short)f2bf(a1.x*b1.x); v[5]=(short)f2bf(a1.y*b1.y);
  v[6]=(short)f2bf(a1.z*b1.z); v[7]=(short)f2bf(a1.w*b1.w);
  return v;
}

// fused prep: [0,1500): statAdd; [1500,1503): w2sum; 1503: w1sum0; [1504,..): betadot
__global__ void k_prep(const float* __restrict__ rel_table, const float* __restrict__ r_query,
                       const float* __restrict__ beta_w, const float* __restrict__ msg_w,
                       const float* __restrict__ msg_b,
                       float* __restrict__ statAdd, float* __restrict__ w2sum,
                       float* __restrict__ w1sum0, float* __restrict__ bdot,
                       float* __restrict__ qdot){
  int blk = blockIdx.x, j = threadIdx.x;   // 64 threads
  if(blk < L_*R_){
    int k = blk/R_, r = blk%R_;
    const float* W3 = msg_w + k*5*D_*D_ + 3*D_*D_;
    const float* rt = rel_table + r*D_;
    float s = msg_b[k*D_+j];
    #pragma unroll
    for(int i=0;i<D_;i++) s += rt[i]*W3[i*D_+j];
    statAdd[(k*R_+r)*D_+j] = s;
  } else if(blk < L_*R_+3){
    int k = blk - L_*R_;
    const float* W2 = msg_w + k*5*D_*D_ + 2*D_*D_;
    float s = 0.f;
    #pragma unroll
    for(int i=0;i<D_;i++) s += W2[i*D_+j];
    w2sum[k*D_+j] = s;
  } else if(blk == L_*R_+3){
    const float* W1 = msg_w + 1*D_*D_;
    float s = 0.f;
    #pragma unroll
    for(int i=0;i<D_;i++) s += W1[i*D_+j];
    w1sum0[j] = s;
  } else {
    int item = blk - (L_*R_+4);
    if(item >= R_+B_) return;
    float x = (item < R_ ? rel_table[item*D_+j] : r_query[(item-R_)*D_+j]) * beta_w[j];
    #pragma unroll
    for(int off=32; off; off>>=1) x += __shfl_xor(x, off, 64);
    if(j==0){ if(item < R_) bdot[item] = x; else qdot[item-R_] = x; }
  }
}

// W0|W4 -> transposed, pre-swizzled bf16: Btw[k] byte (n*256 + (kk*2 ^ ((n&7)<<4))) = W[kk][n]
__global__ void k_prepw(const float* __restrict__ msg_w, unsigned short* __restrict__ Btw){
  int t = blockIdx.x*256 + threadIdx.x;      // L_*64*128 = 24576
  if(t >= L_*8192) return;
  int k = t >> 13, rem = t & 8191;
  int n = rem >> 7, kk = rem & 127;
  const float* W0 = msg_w + k*5*D_*D_;
  float v = (kk<64) ? W0[kk*64+n] : W0[4*D_*D_ + (kk-64)*64+n];
  *(unsigned short*)((char*)Btw + k*16384 + n*256 + ((kk*2) ^ ((n&7)<<4))) = f2bf(v);
}

// conf f32 -> bf16 packed in MFMA A-fragment order:
// chunk[(G*8 + mt*2 + kt2)*64 + lane] (16B) = conf[G*64+mt*16+(lane&15)][kt2*32+(lane>>4)*8 .. +8]
__global__ void k_prepc(const float* __restrict__ conf, unsigned short* __restrict__ confp){
  int t = blockIdx.x*256 + threadIdx.x;      // B_*E_*8
  int seg = t & 7, e = t >> 3;
  int G = e >> 6, eloc = e & 63;
  int chunk = (G*8 + (eloc>>4)*2 + (seg>>2))*64 + (seg&3)*16 + (eloc&15);
  const float* sp = conf + (size_t)e*64 + seg*8;
  float4 u0 = *(const float4*)sp, u1 = *(const float4*)(sp+4);
  union { unsigned short s[8]; uint4 q; } o;
  o.s[0]=f2bf(u0.x); o.s[1]=f2bf(u0.y); o.s[2]=f2bf(u0.z); o.s[3]=f2bf(u0.w);
  o.s[4]=f2bf(u1.x); o.s[5]=f2bf(u1.y); o.s[6]=f2bf(u1.z); o.s[7]=f2bf(u1.w);
  ((uint4*)confp)[chunk] = o.q;
}

// h init; hW1' (layer0, w2sum folded) init; aggr zero
__global__ void k_init(float* __restrict__ h, float* __restrict__ aggr,
                       float* __restrict__ hW1, const float* __restrict__ w1sum0,
                       const float* __restrict__ w2sum){
  int idx = blockIdx.x*256 + threadIdx.x;
  int n = (idx / D_) & (N_-1);
  int j = idx & (D_-1);
  bool z = (n==0);
  h[idx]    = z ? 1.0f : 0.0f;
  hW1[idx]  = z ? (w1sum0[j] + w2sum[j]) : 0.0f;
  aggr[idx] = 0.0f;
}

// MFMA edge kernel, XCD-affine: batch = blockIdx.x & 7 (round-robin dispatch -> one XCD per batch)
__global__ void __launch_bounds__(256,3) k_edge(
    const int* __restrict__ edge_index, const int* __restrict__ rels,
    const float* __restrict__ scores, const int* __restrict__ confm,
    const float* __restrict__ bdot, const float* __restrict__ qdot,
    const float* __restrict__ beta_b,
    const float* __restrict__ h, const float* __restrict__ hW1,
    const float* __restrict__ rel_table, const float* __restrict__ conf,
    const unsigned short* __restrict__ confp, const unsigned short* __restrict__ Btw,
    const float* __restrict__ statAdd, int k, float* __restrict__ aggr){
  __shared__ __align__(16) uint4 Bsh4[1024];   // 16 KB, pre-swizzled [n][kk]

  const int tid = threadIdx.x, wid = tid>>6, lane = tid&63;
  const int b     = blockIdx.x & 7;
  const int chunk = blockIdx.x >> 3;
  const int ebase = b*E_ + chunk*256 + wid*64;
  const int eg  = ebase + lane;
  const int ein = eg & (E_-1);

  // B staging: linear copy of pre-swizzled bf16 (no transpose, no conflicts)
  {
    const uint4* src = (const uint4*)((const char*)Btw + k*16384);
    #pragma unroll
    for(int i=0;i<4;i++) Bsh4[i*256+tid] = src[i*256+tid];
  }

  int   srcv = edge_index[b*2*E_ + ein];
  int   tgtv = edge_index[b*2*E_ + E_ + ein];
  int   relv = rels[eg];
  float beta = sigm(bdot[relv] + qdot[b] + beta_b[0]);
  float gv   = (confm[eg]!=0) ? sigm((scores[eg]-beta)*10.0f) : 0.5f;

  int s_m[4], r_m[4];
  #pragma unroll
  for(int mt=0;mt<4;mt++){
    s_m[mt] = __shfl(srcv, mt*16 + (lane&15));
    r_m[mt] = __shfl(relv, mt*16 + (lane&15));
  }

  // p fragments kt=0 direct to registers
  bf16x8 af0[4];
  #pragma unroll
  for(int mt=0;mt<4;mt++){
    const float* hp = h + (size_t)(b*N_+s_m[mt])*64 + (lane>>4)*8;
    const float* rp = rel_table + (size_t)r_m[mt]*64 + (lane>>4)*8;
    af0[mt] = pk8(*(const float4*)hp, *(const float4*)(hp+4),
                  *(const float4*)rp, *(const float4*)(rp+4));
  }
  // conf fragments
  bf16x8 af2[4][2];
  if(confp){
    const uint4* cp = (const uint4*)confp + (size_t)(ebase>>6)*8*64;
    #pragma unroll
    for(int mt=0;mt<4;mt++)
      #pragma unroll
      for(int kt2=0;kt2<2;kt2++)
        af2[mt][kt2] = *(const bf16x8*)(cp + (mt*2+kt2)*64 + lane);
  } else {
    const float* cb = conf + (size_t)ebase*64;
    #pragma unroll
    for(int mt=0;mt<4;mt++)
      #pragma unroll
      for(int kt2=0;kt2<2;kt2++){
        const float* src = cb + (size_t)(mt*16 + (lane&15))*64 + kt2*32 + (lane>>4)*8;
        float4 u0 = *(const float4*)(src);
        float4 u1 = *(const float4*)(src+4);
        bf16x8 v;
        v[0]=(short)f2bf(u0.x); v[1]=(short)f2bf(u0.y); v[2]=(short)f2bf(u0.z); v[3]=(short)f2bf(u0.w);
        v[4]=(short)f2bf(u1.x); v[5]=(short)f2bf(u1.y); v[6]=(short)f2bf(u1.z); v[7]=(short)f2bf(u1.w);
        af2[mt][kt2] = v;
      }
  }
  __syncthreads();

  f32x4 acc[4][4];
  #pragma unroll
  for(int mt=0;mt<4;mt++)
    #pragma unroll
    for(int nt=0;nt<4;nt++) acc[mt][nt] = (f32x4){0.f,0.f,0.f,0.f};

  // kt=0: p @ W0[:,0:32]; prefetch kt=1 p-fragments
  bf16x8 af1[4];
  {
    bf16x8 bfr[4];
    int kbyte = (lane>>4)*16;
    #pragma unroll
    for(int nt=0;nt<4;nt++){
      int n = nt*16 + (lane&15);
      bfr[nt] = *(const bf16x8*)((const char*)Bsh4 + n*256 + (kbyte ^ ((n&7)<<4)));
    }
    #pragma unroll
    for(int mt=0;mt<4;mt++){
      const float* hp = h + (size_t)(b*N_+s_m[mt])*64 + 32 + (lane>>4)*8;
      const float* rp = rel_table + (size_t)r_m[mt]*64 + 32 + (lane>>4)*8;
      af1[mt] = pk8(*(const float4*)hp, *(const float4*)(hp+4),
                    *(const float4*)rp, *(const float4*)(rp+4));
    }
    #pragma unroll
    for(int mt=0;mt<4;mt++)
      #pragma unroll
      for(int nt=0;nt<4;nt++)
        acc[mt][nt] = __builtin_amdgcn_mfma_f32_16x16x32_bf16(af0[mt], bfr[nt], acc[mt][nt], 0,0,0);
  }
  // kt=1
  {
    bf16x8 bfr[4];
    int kbyte = 64 + (lane>>4)*16;
    #pragma unroll
    for(int nt=0;nt<4;nt++){
      int n = nt*16 + (lane&15);
      bfr[nt] = *(const bf16x8*)((const char*)Bsh4 + n*256 + (kbyte ^ ((n&7)<<4)));
    }
    #pragma unroll
    for(int mt=0;mt<4;mt++)
      #pragma unroll
      for(int nt=0;nt<4;nt++)
        acc[mt][nt] = __builtin_amdgcn_mfma_f32_16x16x32_bf16(af1[mt], bfr[nt], acc[mt][nt], 0,0,0);
  }
  // conf @ W4
  #pragma unroll
  for(int kt2=0;kt2<2;kt2++){
    bf16x8 bfr[4];
    int kbyte = 128 + kt2*64 + (lane>>4)*16;
    #pragma unroll
    for(int nt=0;nt<4;nt++){
      int n = nt*16 + (lane&15);
      bfr[nt] = *(const bf16x8*)((const char*)Bsh4 + n*256 + (kbyte ^ ((n&7)<<4)));
    }
    #pragma unroll
    for(int mt=0;mt<4;mt++)
      #pragma unroll
      for(int nt=0;nt<4;nt++)
        acc[mt][nt] = __builtin_amdgcn_mfma_f32_16x16x32_bf16(af2[mt][kt2], bfr[nt], acc[mt][nt], 0,0,0);
  }

  // epilogue: one 64B line per 16-lane group per atomic instruction
  #pragma unroll
  for(int mt=0;mt<4;mt++){
    #pragma unroll
    for(int jr=0;jr<4;jr++){
      int eloc  = mt*16 + (lane>>4)*4 + jr;
      int tgt_e = __shfl(tgtv, eloc);
      int src_e = __shfl(srcv, eloc);
      int r_e   = __shfl(relv, eloc);
      float g_e = __shfl(gv,   eloc);
      const float* sa = statAdd + (size_t)(k*R_ + r_e)*64;
      const float* hw = hW1 + (size_t)(b*N_ + src_e)*64;
      float* ar = aggr + (size_t)(b*N_ + tgt_e)*64;
      #pragma unroll
      for(int nt=0;nt<4;nt++){
        int j = nt*16 + (lane&15);
        float v = acc[mt][nt][jr] + sa[j] + hw[j];
        v = fmaxf(v, 0.f) * g_e;
        unsafeAtomicAdd(ar + j, v);
      }
    }
  }
}

// h = LN(h + aggr@U_k + b); aggr = 0; hW1' = h@W1_{k+1} + (n==0)*w2sum_{k+1}; ctx out
__global__ void k_update(float* __restrict__ aggr, const float* __restrict__ upd_w,
                         const float* __restrict__ upd_b, const float* __restrict__ ln_g,
                         const float* __restrict__ ln_b, const float* __restrict__ msg_w,
                         const float* __restrict__ w2sum, int k,
                         float* __restrict__ h, float* __restrict__ hW1,
                         float* __restrict__ out){
  int node = blockIdx.x*4 + (threadIdx.x>>6);
  int j = threadIdx.x & 63;
  int b = node >> 12;
  int n = node & (N_-1);
  size_t idx = (size_t)node*64 + j;
  const float* U = upd_w + k*D_*D_;
  float a = aggr[idx];
  aggr[idx] = 0.0f;
  float c0 = h[idx] + upd_b[k*D_+j], c1 = 0.f, c2 = 0.f, c3 = 0.f;
  #pragma unroll
  for(int i=0;i<16;i++){
    c0 += __shfl(a, i,    64) * U[(i)*D_+j];
    c1 += __shfl(a, i+16, 64) * U[(i+16)*D_+j];
    c2 += __shfl(a, i+32, 64) * U[(i+32)*D_+j];
    c3 += __shfl(a, i+48, 64) * U[(i+48)*D_+j];
  }
  float acc = (c0+c1)+(c2+c3);
  float s = acc, sq = acc*acc;
  #pragma unroll
  for(int off=32; off; off>>=1){
    s  += __shfl_xor(s,  off, 64);
    sq += __shfl_xor(sq, off, 64);
  }
  float mean = s * (1.0f/64.0f);
  float var  = sq * (1.0f/64.0f) - mean*mean;
  float y = (acc - mean)*rsqrtf(var + EPS_)*ln_g[j] + ln_b[j];
  h[idx] = y;
  if(n==0) out[(b*L_+k)*D_+j] = y;
  if(k < L_-1){
    const float* W1 = msg_w + (k+1)*5*D_*D_ + D_*D_;
    float w0 = 0.f, w1 = 0.f, w2 = 0.f, w3 = 0.f;
    #pragma unroll
    for(int i=0;i<16;i++){
      w0 += __shfl(y, i,    64) * W1[(i)*D_+j];
      w1 += __shfl(y, i+16, 64) * W1[(i+16)*D_+j];
      w2 += __shfl(y, i+32, 64) * W1[(i+32)*D_+j];
      w3 += __shfl(y, i+48, 64) * W1[(i+48)*D_+j];
    }
    hW1[idx] = (w0+w1)+(w2+w3) + ((n==0) ? w2sum[(k+1)*D_+j] : 0.0f);
  }
}

extern "C" void kernel_launch(void* const* d_in, const int* in_sizes, int n_in,
                              void* d_out, int out_size, void* d_ws, size_t ws_size,
                              hipStream_t stream) {
  const int*   edge_index = (const int*)d_in[0];
  const int*   rels       = (const int*)d_in[1];
  const float* scores     = (const float*)d_in[2];
  const int*   confm      = (const int*)d_in[3];
  const float* r_query    = (const float*)d_in[6];
  const float* rel_table  = (const float*)d_in[7];
  const float* conf       = (const float*)d_in[8];
  const float* beta_w     = (const float*)d_in[9];
  const float* beta_b     = (const float*)d_in[10];
  const float* msg_w      = (const float*)d_in[11];
  const float* msg_b      = (const float*)d_in[12];
  const float* upd_w      = (const float*)d_in[13];
  const float* upd_b      = (const float*)d_in[14];
  const float* ln_g       = (const float*)d_in[15];
  const float* ln_b       = (const float*)d_in[16];
  float* out = (float*)d_out;

  float* ws      = (float*)d_ws;
  float* h       = ws;                        // 2,097,152
  float* aggr    = h    + B_*N_*D_;           // 2,097,152
  float* hW1     = aggr + B_*N_*D_;           // 2,097,152
  float* statAdd = hW1  + B_*N_*D_;           // 96,000
  float* w2sum   = statAdd + L_*R_*D_;        // 192
  float* w1sum0  = w2sum + L_*D_;             // 64
  float* bdot    = w1sum0 + D_;               // 512
  float* qdot    = bdot + 512;                // 64 (padded)
  unsigned short* Btw = (unsigned short*)(qdot + 64);          // 24,576 ushorts
  unsigned short* confp = (unsigned short*)(((float*)Btw) + 12288);  // 16,777,216 ushorts

  size_t need_packed = ((size_t)(confp - (unsigned short*)d_ws))*2 + (size_t)B_*E_*D_*2;
  bool use_packed = ws_size >= need_packed;

  k_prep<<<L_*R_+4+R_+B_, 64, 0, stream>>>(rel_table, r_query, beta_w, msg_w, msg_b,
                                           statAdd, w2sum, w1sum0, bdot, qdot);
  k_prepw<<<(L_*8192+255)/256, 256, 0, stream>>>(msg_w, Btw);
  if(use_packed)
    k_prepc<<<(B_*E_*8)/256, 256, 0, stream>>>(conf, confp);
  k_init<<<(B_*N_*D_)/256, 256, 0, stream>>>(h, aggr, hW1, w1sum0, w2sum);

  const unsigned short* confp_arg = use_packed ? confp : (const unsigned short*)nullptr;
  for(int k=0;k<L_;k++){
    k_edge<<<(B_*E_)/256, 256, 0, stream>>>(edge_index, rels, scores, confm, bdot, qdot,
                                            beta_b, h, hW1, rel_table, conf, confp_arg,
                                            Btw, statAdd, k, aggr);
    k_update<<<(B_*N_)/4, 256, 0, stream>>>(aggr, upd_w, upd_b, ln_g, ln_b, msg_w,
                                            w2sum, k, h, hW1, out);
  }
}

// Round 7
// 431.751 us; speedup vs baseline: 1.1026x; 1.1026x over previous
//
#include <hip/hip_runtime.h>

#define B_ 8
#define E_ 32768
#define N_ 4096
#define D_ 64
#define R_ 500
#define L_ 3
#define EPS_ 1e-5f

typedef short bf16x8 __attribute__((ext_vector_type(8)));
typedef float f32x4 __attribute__((ext_vector_type(4)));

__device__ __forceinline__ float sigm(float x){ return 1.0f/(1.0f+__expf(-x)); }
__device__ __forceinline__ unsigned short f2bf(float x){
  unsigned u = __float_as_uint(x);
  u += 0x7fffu + ((u>>16)&1u);
  return (unsigned short)(u>>16);
}
__device__ __forceinline__ bf16x8 pk8(float4 a0, float4 a1, float4 b0, float4 b1){
  bf16x8 v;
  v[0]=(short)f2bf(a0.x*b0.x); v[1]=(short)f2bf(a0.y*b0.y);
  v[2]=(short)f2bf(a0.z*b0.z); v[3]=(short)f2bf(a0.w*b0.w);
  v[4]=(short)f2bf(a1.x*b1.x); v[5]=(short)f2bf(a1.y*b1.y);
  v[6]=(short)f2bf(a1.z*b1.z); v[7]=(short)f2bf(a1.w*b1.w);
  return v;
}

// fused prep: [0,1500): statAdd; [1500,1503): w2sum; 1503: w1sum0; [1504,..): betadot
__global__ void k_prep(const float* __restrict__ rel_table, const float* __restrict__ r_query,
                       const float* __restrict__ beta_w, const float* __restrict__ msg_w,
                       const float* __restrict__ msg_b,
                       float* __restrict__ statAdd, float* __restrict__ w2sum,
                       float* __restrict__ w1sum0, float* __restrict__ bdot,
                       float* __restrict__ qdot){
  int blk = blockIdx.x, j = threadIdx.x;   // 64 threads
  if(blk < L_*R_){
    int k = blk/R_, r = blk%R_;
    const float* W3 = msg_w + k*5*D_*D_ + 3*D_*D_;
    const float* rt = rel_table + r*D_;
    float s = msg_b[k*D_+j];
    #pragma unroll
    for(int i=0;i<D_;i++) s += rt[i]*W3[i*D_+j];
    statAdd[(k*R_+r)*D_+j] = s;
  } else if(blk < L_*R_+3){
    int k = blk - L_*R_;
    const float* W2 = msg_w + k*5*D_*D_ + 2*D_*D_;
    float s = 0.f;
    #pragma unroll
    for(int i=0;i<D_;i++) s += W2[i*D_+j];
    w2sum[k*D_+j] = s;
  } else if(blk == L_*R_+3){
    const float* W1 = msg_w + 1*D_*D_;
    float s = 0.f;
    #pragma unroll
    for(int i=0;i<D_;i++) s += W1[i*D_+j];
    w1sum0[j] = s;
  } else {
    int item = blk - (L_*R_+4);
    if(item >= R_+B_) return;
    float x = (item < R_ ? rel_table[item*D_+j] : r_query[(item-R_)*D_+j]) * beta_w[j];
    #pragma unroll
    for(int off=32; off; off>>=1) x += __shfl_xor(x, off, 64);
    if(j==0){ if(item < R_) bdot[item] = x; else qdot[item-R_] = x; }
  }
}

// W0|W4 -> transposed, pre-swizzled bf16
__global__ void k_prepw(const float* __restrict__ msg_w, unsigned short* __restrict__ Btw){
  int t = blockIdx.x*256 + threadIdx.x;      // L_*8192
  if(t >= L_*8192) return;
  int k = t >> 13, rem = t & 8191;
  int n = rem >> 7, kk = rem & 127;
  const float* W0 = msg_w + k*5*D_*D_;
  float v = (kk<64) ? W0[kk*64+n] : W0[4*D_*D_ + (kk-64)*64+n];
  *(unsigned short*)((char*)Btw + k*16384 + n*256 + ((kk*2) ^ ((n&7)<<4))) = f2bf(v);
}

// h init; hW1' (layer0, w2sum folded) init
__global__ void k_init(float* __restrict__ h, float* __restrict__ hW1,
                       const float* __restrict__ w1sum0, const float* __restrict__ w2sum){
  int idx = blockIdx.x*256 + threadIdx.x;
  int n = (idx / D_) & (N_-1);
  int j = idx & (D_-1);
  bool z = (n==0);
  h[idx]   = z ? 1.0f : 0.0f;
  hW1[idx] = z ? (w1sum0[j] + w2sum[j]) : 0.0f;
}

// CSR build: histogram of tgt
__global__ void k_hist(const int* __restrict__ edge_index, int* __restrict__ deg){
  int idx = blockIdx.x*256 + threadIdx.x;    // B*E
  int b = idx >> 15, e = idx & (E_-1);
  int tgt = edge_index[b*2*E_ + E_ + e];
  atomicAdd(&deg[b*N_ + tgt], 1);
}

// per-batch exclusive scan of deg -> off, cursor (8 blocks x 1024 thr, 4 elems/thr)
__global__ void k_scan(const int* __restrict__ deg, int* __restrict__ off,
                       int* __restrict__ cursor){
  int b = blockIdx.x, t = threadIdx.x;
  int base = b*N_ + t*4;
  int v0 = deg[base], v1 = deg[base+1], v2 = deg[base+2], v3 = deg[base+3];
  int s = v0+v1+v2+v3;
  int lane = t & 63, w = t >> 6;             // 16 waves
  int x = s;
  #pragma unroll
  for(int d=1; d<64; d<<=1){
    int y = __shfl_up(x, d, 64);
    if(lane >= d) x += y;
  }
  int wave_excl = x - s;                     // exclusive within wave
  __shared__ int wsum[16];
  if(lane==63) wsum[w] = x;
  __syncthreads();
  int wbase = 0;
  for(int i=0;i<w;i++) wbase += wsum[i];
  int excl = wbase + wave_excl;
  off[base]   = excl;           cursor[base]   = excl;
  off[base+1] = excl+v0;        cursor[base+1] = excl+v0;
  off[base+2] = excl+v0+v1;     cursor[base+2] = excl+v0+v1;
  off[base+3] = excl+v0+v1+v2;  cursor[base+3] = excl+v0+v1+v2;
}

__global__ void k_fill(const int* __restrict__ edge_index, int* __restrict__ cursor,
                       unsigned short* __restrict__ eidlist){
  int idx = blockIdx.x*256 + threadIdx.x;    // B*E
  int b = idx >> 15, e = idx & (E_-1);
  int tgt = edge_index[b*2*E_ + E_ + e];
  int pos = atomicAdd(&cursor[b*N_ + tgt], 1);
  eidlist[b*E_ + pos] = (unsigned short)e;
}

// MFMA edge kernel -> dense bf16 message rows (no atomics)
__global__ void __launch_bounds__(256,3) k_edge(
    const int* __restrict__ edge_index, const int* __restrict__ rels,
    const float* __restrict__ scores, const int* __restrict__ confm,
    const float* __restrict__ bdot, const float* __restrict__ qdot,
    const float* __restrict__ beta_b,
    const float* __restrict__ h, const float* __restrict__ hW1,
    const float* __restrict__ rel_table, const float* __restrict__ conf,
    const unsigned short* __restrict__ Btw, const float* __restrict__ statAdd,
    int k, unsigned short* __restrict__ wmsg){
  __shared__ __align__(16) uint4 Bsh4[1024];   // 16 KB, pre-swizzled [n][kk]

  const int tid = threadIdx.x, wid = tid>>6, lane = tid&63;
  const int b     = blockIdx.x & 7;          // XCD-affine batch
  const int chunk = blockIdx.x >> 3;
  const int ebase = b*E_ + chunk*256 + wid*64;
  const int eg  = ebase + lane;
  const int ein = eg & (E_-1);

  // B staging: linear copy of pre-swizzled bf16
  {
    const uint4* src = (const uint4*)((const char*)Btw + k*16384);
    #pragma unroll
    for(int i=0;i<4;i++) Bsh4[i*256+tid] = src[i*256+tid];
  }

  int   srcv = edge_index[b*2*E_ + ein];
  int   relv = rels[eg];
  float beta = sigm(bdot[relv] + qdot[b] + beta_b[0]);
  float gv   = (confm[eg]!=0) ? sigm((scores[eg]-beta)*10.0f) : 0.5f;

  int s_m[4], r_m[4];
  #pragma unroll
  for(int mt=0;mt<4;mt++){
    s_m[mt] = __shfl(srcv, mt*16 + (lane&15));
    r_m[mt] = __shfl(relv, mt*16 + (lane&15));
  }

  // p fragments kt=0 direct to registers
  bf16x8 af0[4];
  #pragma unroll
  for(int mt=0;mt<4;mt++){
    const float* hp = h + (size_t)(b*N_+s_m[mt])*64 + (lane>>4)*8;
    const float* rp = rel_table + (size_t)r_m[mt]*64 + (lane>>4)*8;
    af0[mt] = pk8(*(const float4*)hp, *(const float4*)(hp+4),
                  *(const float4*)rp, *(const float4*)(rp+4));
  }
  // conf fragments: direct global load, f32->bf16 in regs
  bf16x8 af2[4][2];
  {
    const float* cb = conf + (size_t)ebase*64;
    #pragma unroll
    for(int mt=0;mt<4;mt++)
      #pragma unroll
      for(int kt2=0;kt2<2;kt2++){
        const float* src = cb + (size_t)(mt*16 + (lane&15))*64 + kt2*32 + (lane>>4)*8;
        float4 u0 = *(const float4*)(src);
        float4 u1 = *(const float4*)(src+4);
        bf16x8 v;
        v[0]=(short)f2bf(u0.x); v[1]=(short)f2bf(u0.y); v[2]=(short)f2bf(u0.z); v[3]=(short)f2bf(u0.w);
        v[4]=(short)f2bf(u1.x); v[5]=(short)f2bf(u1.y); v[6]=(short)f2bf(u1.z); v[7]=(short)f2bf(u1.w);
        af2[mt][kt2] = v;
      }
  }
  __syncthreads();

  f32x4 acc[4][4];
  #pragma unroll
  for(int mt=0;mt<4;mt++)
    #pragma unroll
    for(int nt=0;nt<4;nt++) acc[mt][nt] = (f32x4){0.f,0.f,0.f,0.f};

  // kt=0: p @ W0[0:32]; prefetch kt=1 p-fragments
  bf16x8 af1[4];
  {
    bf16x8 bfr[4];
    int kbyte = (lane>>4)*16;
    #pragma unroll
    for(int nt=0;nt<4;nt++){
      int n = nt*16 + (lane&15);
      bfr[nt] = *(const bf16x8*)((const char*)Bsh4 + n*256 + (kbyte ^ ((n&7)<<4)));
    }
    #pragma unroll
    for(int mt=0;mt<4;mt++){
      const float* hp = h + (size_t)(b*N_+s_m[mt])*64 + 32 + (lane>>4)*8;
      const float* rp = rel_table + (size_t)r_m[mt]*64 + 32 + (lane>>4)*8;
      af1[mt] = pk8(*(const float4*)hp, *(const float4*)(hp+4),
                    *(const float4*)rp, *(const float4*)(rp+4));
    }
    #pragma unroll
    for(int mt=0;mt<4;mt++)
      #pragma unroll
      for(int nt=0;nt<4;nt++)
        acc[mt][nt] = __builtin_amdgcn_mfma_f32_16x16x32_bf16(af0[mt], bfr[nt], acc[mt][nt], 0,0,0);
  }
  // kt=1
  {
    bf16x8 bfr[4];
    int kbyte = 64 + (lane>>4)*16;
    #pragma unroll
    for(int nt=0;nt<4;nt++){
      int n = nt*16 + (lane&15);
      bfr[nt] = *(const bf16x8*)((const char*)Bsh4 + n*256 + (kbyte ^ ((n&7)<<4)));
    }
    #pragma unroll
    for(int mt=0;mt<4;mt++)
      #pragma unroll
      for(int nt=0;nt<4;nt++)
        acc[mt][nt] = __builtin_amdgcn_mfma_f32_16x16x32_bf16(af1[mt], bfr[nt], acc[mt][nt], 0,0,0);
  }
  // conf @ W4
  #pragma unroll
  for(int kt2=0;kt2<2;kt2++){
    bf16x8 bfr[4];
    int kbyte = 128 + kt2*64 + (lane>>4)*16;
    #pragma unroll
    for(int nt=0;nt<4;nt++){
      int n = nt*16 + (lane&15);
      bfr[nt] = *(const bf16x8*)((const char*)Bsh4 + n*256 + (kbyte ^ ((n&7)<<4)));
    }
    #pragma unroll
    for(int mt=0;mt<4;mt++)
      #pragma unroll
      for(int nt=0;nt<4;nt++)
        acc[mt][nt] = __builtin_amdgcn_mfma_f32_16x16x32_bf16(af2[mt][kt2], bfr[nt], acc[mt][nt], 0,0,0);
  }

  // epilogue: relu(D + statAdd + hW1')*gate -> bf16 row store (no atomics)
  #pragma unroll
  for(int mt=0;mt<4;mt++){
    #pragma unroll
    for(int jr=0;jr<4;jr++){
      int eloc  = mt*16 + (lane>>4)*4 + jr;
      int src_e = __shfl(srcv, eloc);
      int r_e   = __shfl(relv, eloc);
      float g_e = __shfl(gv,   eloc);
      const float* sa = statAdd + (size_t)(k*R_ + r_e)*64;
      const float* hw = hW1 + (size_t)(b*N_ + src_e)*64;
      unsigned short* wr = wmsg + (size_t)(ebase + eloc)*64;
      #pragma unroll
      for(int nt=0;nt<4;nt++){
        int j = nt*16 + (lane&15);
        float v = acc[mt][nt][jr] + sa[j] + hw[j];
        v = fmaxf(v, 0.f) * g_e;
        wr[j] = f2bf(v);
      }
    }
  }
}

// gather incident messages (CSR) + h=LN(h+aggr@U+b); hW1' for next layer; ctx out
__global__ void k_update(const unsigned short* __restrict__ wmsg,
                         const int* __restrict__ off, const int* __restrict__ deg,
                         const unsigned short* __restrict__ eidlist,
                         const float* __restrict__ upd_w, const float* __restrict__ upd_b,
                         const float* __restrict__ ln_g, const float* __restrict__ ln_b,
                         const float* __restrict__ msg_w, const float* __restrict__ w2sum,
                         int k, float* __restrict__ h, float* __restrict__ hW1,
                         float* __restrict__ out){
  int node = blockIdx.x*4 + (threadIdx.x>>6);
  int j = threadIdx.x & 63;
  int b = node >> 12;
  int n = node & (N_-1);
  size_t idx = (size_t)node*64 + j;

  // CSR gather, f32 accumulate
  int start = off[b*N_ + n];
  int dg    = deg[b*N_ + n];
  const unsigned short* wb = wmsg + (size_t)b*E_*64;
  const unsigned short* el = eidlist + b*E_;
  float a = 0.f;
  for(int i=0;i<dg;i++){
    int e = el[start+i];
    unsigned u = wb[(size_t)e*64 + j];
    a += __uint_as_float(u << 16);
  }

  const float* U = upd_w + k*D_*D_;
  float c0 = h[idx] + upd_b[k*D_+j], c1 = 0.f, c2 = 0.f, c3 = 0.f;
  #pragma unroll
  for(int i=0;i<16;i++){
    c0 += __shfl(a, i,    64) * U[(i)*D_+j];
    c1 += __shfl(a, i+16, 64) * U[(i+16)*D_+j];
    c2 += __shfl(a, i+32, 64) * U[(i+32)*D_+j];
    c3 += __shfl(a, i+48, 64) * U[(i+48)*D_+j];
  }
  float acc = (c0+c1)+(c2+c3);
  float s = acc, sq = acc*acc;
  #pragma unroll
  for(int o=32; o; o>>=1){
    s  += __shfl_xor(s,  o, 64);
    sq += __shfl_xor(sq, o, 64);
  }
  float mean = s * (1.0f/64.0f);
  float var  = sq * (1.0f/64.0f) - mean*mean;
  float y = (acc - mean)*rsqrtf(var + EPS_)*ln_g[j] + ln_b[j];
  h[idx] = y;
  if(n==0) out[(b*L_+k)*D_+j] = y;
  if(k < L_-1){
    const float* W1 = msg_w + (k+1)*5*D_*D_ + D_*D_;
    float w0 = 0.f, w1 = 0.f, w2 = 0.f, w3 = 0.f;
    #pragma unroll
    for(int i=0;i<16;i++){
      w0 += __shfl(y, i,    64) * W1[(i)*D_+j];
      w1 += __shfl(y, i+16, 64) * W1[(i+16)*D_+j];
      w2 += __shfl(y, i+32, 64) * W1[(i+32)*D_+j];
      w3 += __shfl(y, i+48, 64) * W1[(i+48)*D_+j];
    }
    hW1[idx] = (w0+w1)+(w2+w3) + ((n==0) ? w2sum[(k+1)*D_+j] : 0.0f);
  }
}

extern "C" void kernel_launch(void* const* d_in, const int* in_sizes, int n_in,
                              void* d_out, int out_size, void* d_ws, size_t ws_size,
                              hipStream_t stream) {
  const int*   edge_index = (const int*)d_in[0];
  const int*   rels       = (const int*)d_in[1];
  const float* scores     = (const float*)d_in[2];
  const int*   confm      = (const int*)d_in[3];
  const float* r_query    = (const float*)d_in[6];
  const float* rel_table  = (const float*)d_in[7];
  const float* conf       = (const float*)d_in[8];
  const float* beta_w     = (const float*)d_in[9];
  const float* beta_b     = (const float*)d_in[10];
  const float* msg_w      = (const float*)d_in[11];
  const float* msg_b      = (const float*)d_in[12];
  const float* upd_w      = (const float*)d_in[13];
  const float* upd_b      = (const float*)d_in[14];
  const float* ln_g       = (const float*)d_in[15];
  const float* ln_b       = (const float*)d_in[16];
  float* out = (float*)d_out;

  float* ws      = (float*)d_ws;
  float* h       = ws;                          // 2,097,152 f
  float* hW1     = h + B_*N_*D_;                // 2,097,152 f
  float* statAdd = hW1 + B_*N_*D_;              // 96,000 f
  float* w2sum   = statAdd + L_*R_*D_;          // 192 f
  float* w1sum0  = w2sum + L_*D_;               // 64 f
  float* bdot    = w1sum0 + D_;                 // 512 f
  float* qdot    = bdot + 512;                  // 64 f
  unsigned short* Btw = (unsigned short*)(qdot + 64);      // 24,576 u16
  int* deg    = (int*)(((float*)Btw) + 12288);  // 32,768 i32
  int* off    = deg + B_*N_;                    // 32,768 i32
  int* cursor = off + B_*N_;                    // 32,768 i32
  unsigned short* eidlist = (unsigned short*)(cursor + B_*N_);   // 262,144 u16
  unsigned short* wmsg    = eidlist + B_*E_;    // 16,777,216 u16 (32 MB)

  k_prep<<<L_*R_+4+R_+B_, 64, 0, stream>>>(rel_table, r_query, beta_w, msg_w, msg_b,
                                           statAdd, w2sum, w1sum0, bdot, qdot);
  k_prepw<<<(L_*8192+255)/256, 256, 0, stream>>>(msg_w, Btw);
  k_init<<<(B_*N_*D_)/256, 256, 0, stream>>>(h, hW1, w1sum0, w2sum);
  hipMemsetAsync(deg, 0, (size_t)B_*N_*sizeof(int), stream);
  k_hist<<<(B_*E_)/256, 256, 0, stream>>>(edge_index, deg);
  k_scan<<<B_, 1024, 0, stream>>>(deg, off, cursor);
  k_fill<<<(B_*E_)/256, 256, 0, stream>>>(edge_index, cursor, eidlist);

  for(int k=0;k<L_;k++){
    k_edge<<<(B_*E_)/256, 256, 0, stream>>>(edge_index, rels, scores, confm, bdot, qdot,
                                            beta_b, h, hW1, rel_table, conf, Btw,
                                            statAdd, k, wmsg);
    k_update<<<(B_*N_)/4, 256, 0, stream>>>(wmsg, off, deg, eidlist, upd_w, upd_b,
                                            ln_g, ln_b, msg_w, w2sum, k, h, hW1, out);
  }
}

// Round 8
// 348.948 us; speedup vs baseline: 1.3642x; 1.2373x over previous
//
#include <hip/hip_runtime.h>

#define B_ 8
#define E_ 32768
#define N_ 4096
#define D_ 64
#define R_ 500
#define L_ 3
#define EPS_ 1e-5f

typedef short bf16x8 __attribute__((ext_vector_type(8)));
typedef float f32x4 __attribute__((ext_vector_type(4)));

__device__ __forceinline__ float sigm(float x){ return 1.0f/(1.0f+__expf(-x)); }
__device__ __forceinline__ unsigned short f2bf(float x){
  unsigned u = __float_as_uint(x);
  u += 0x7fffu + ((u>>16)&1u);
  return (unsigned short)(u>>16);
}
__device__ __forceinline__ bf16x8 pk8(float4 a0, float4 a1, float4 b0, float4 b1){
  bf16x8 v;
  v[0]=(short)f2bf(a0.x*b0.x); v[1]=(short)f2bf(a0.y*b0.y);
  v[2]=(short)f2bf(a0.z*b0.z); v[3]=(short)f2bf(a0.w*b0.w);
  v[4]=(short)f2bf(a1.x*b1.x); v[5]=(short)f2bf(a1.y*b1.y);
  v[6]=(short)f2bf(a1.z*b1.z); v[7]=(short)f2bf(a1.w*b1.w);
  return v;
}

// fused prep: [0,1500): statAdd; [1500,1503): w2sum; 1503: w1sum0; [1504,..): betadot
__global__ void k_prep(const float* __restrict__ rel_table, const float* __restrict__ r_query,
                       const float* __restrict__ beta_w, const float* __restrict__ msg_w,
                       const float* __restrict__ msg_b,
                       float* __restrict__ statAdd, float* __restrict__ w2sum,
                       float* __restrict__ w1sum0, float* __restrict__ bdot,
                       float* __restrict__ qdot){
  int blk = blockIdx.x, j = threadIdx.x;   // 64 threads
  if(blk < L_*R_){
    int k = blk/R_, r = blk%R_;
    const float* W3 = msg_w + k*5*D_*D_ + 3*D_*D_;
    const float* rt = rel_table + r*D_;
    float s = msg_b[k*D_+j];
    #pragma unroll
    for(int i=0;i<D_;i++) s += rt[i]*W3[i*D_+j];
    statAdd[(k*R_+r)*D_+j] = s;
  } else if(blk < L_*R_+3){
    int k = blk - L_*R_;
    const float* W2 = msg_w + k*5*D_*D_ + 2*D_*D_;
    float s = 0.f;
    #pragma unroll
    for(int i=0;i<D_;i++) s += W2[i*D_+j];
    w2sum[k*D_+j] = s;
  } else if(blk == L_*R_+3){
    const float* W1 = msg_w + 1*D_*D_;
    float s = 0.f;
    #pragma unroll
    for(int i=0;i<D_;i++) s += W1[i*D_+j];
    w1sum0[j] = s;
  } else {
    int item = blk - (L_*R_+4);
    if(item >= R_+B_) return;
    float x = (item < R_ ? rel_table[item*D_+j] : r_query[(item-R_)*D_+j]) * beta_w[j];
    #pragma unroll
    for(int off=32; off; off>>=1) x += __shfl_xor(x, off, 64);
    if(j==0){ if(item < R_) bdot[item] = x; else qdot[item-R_] = x; }
  }
}

// W0|W4 -> transposed, pre-swizzled bf16
__global__ void k_prepw(const float* __restrict__ msg_w, unsigned short* __restrict__ Btw){
  int t = blockIdx.x*256 + threadIdx.x;      // L_*8192
  if(t >= L_*8192) return;
  int k = t >> 13, rem = t & 8191;
  int n = rem >> 7, kk = rem & 127;
  const float* W0 = msg_w + k*5*D_*D_;
  float v = (kk<64) ? W0[kk*64+n] : W0[4*D_*D_ + (kk-64)*64+n];
  *(unsigned short*)((char*)Btw + k*16384 + n*256 + ((kk*2) ^ ((n&7)<<4))) = f2bf(v);
}

// h init; hW1' (layer0, w2sum folded) init
__global__ void k_init(float* __restrict__ h, float* __restrict__ hW1,
                       const float* __restrict__ w1sum0, const float* __restrict__ w2sum){
  int idx = blockIdx.x*256 + threadIdx.x;
  int n = (idx / D_) & (N_-1);
  int j = idx & (D_-1);
  bool z = (n==0);
  h[idx]   = z ? 1.0f : 0.0f;
  hW1[idx] = z ? (w1sum0[j] + w2sum[j]) : 0.0f;
}

// CSR build: histogram of tgt
__global__ void k_hist(const int* __restrict__ edge_index, int* __restrict__ deg){
  int idx = blockIdx.x*256 + threadIdx.x;    // B*E
  int b = idx >> 15, e = idx & (E_-1);
  int tgt = edge_index[b*2*E_ + E_ + e];
  atomicAdd(&deg[b*N_ + tgt], 1);
}

// per-batch exclusive scan of deg -> off, cursor (8 blocks x 1024 thr, 4 elems/thr)
__global__ void k_scan(const int* __restrict__ deg, int* __restrict__ off,
                       int* __restrict__ cursor){
  int b = blockIdx.x, t = threadIdx.x;
  int base = b*N_ + t*4;
  int v0 = deg[base], v1 = deg[base+1], v2 = deg[base+2], v3 = deg[base+3];
  int s = v0+v1+v2+v3;
  int lane = t & 63, w = t >> 6;             // 16 waves
  int x = s;
  #pragma unroll
  for(int d=1; d<64; d<<=1){
    int y = __shfl_up(x, d, 64);
    if(lane >= d) x += y;
  }
  int wave_excl = x - s;                     // exclusive within wave
  __shared__ int wsum[16];
  if(lane==63) wsum[w] = x;
  __syncthreads();
  int wbase = 0;
  for(int i=0;i<w;i++) wbase += wsum[i];
  int excl = wbase + wave_excl;
  off[base]   = excl;           cursor[base]   = excl;
  off[base+1] = excl+v0;        cursor[base+1] = excl+v0;
  off[base+2] = excl+v0+v1;     cursor[base+2] = excl+v0+v1;
  off[base+3] = excl+v0+v1+v2;  cursor[base+3] = excl+v0+v1+v2;
}

__global__ void k_fill(const int* __restrict__ edge_index, int* __restrict__ cursor,
                       unsigned short* __restrict__ eidlist){
  int idx = blockIdx.x*256 + threadIdx.x;    // B*E
  int b = idx >> 15, e = idx & (E_-1);
  int tgt = edge_index[b*2*E_ + E_ + e];
  int pos = atomicAdd(&cursor[b*N_ + tgt], 1);
  eidlist[b*E_ + pos] = (unsigned short)e;
}

// MFMA edge kernel -> dense bf16 message rows (no atomics)
__global__ void __launch_bounds__(256,3) k_edge(
    const int* __restrict__ edge_index, const int* __restrict__ rels,
    const float* __restrict__ scores, const int* __restrict__ confm,
    const float* __restrict__ bdot, const float* __restrict__ qdot,
    const float* __restrict__ beta_b,
    const float* __restrict__ h, const float* __restrict__ hW1,
    const float* __restrict__ rel_table, const float* __restrict__ conf,
    const unsigned short* __restrict__ Btw, const float* __restrict__ statAdd,
    int k, unsigned short* __restrict__ wmsg){
  __shared__ __align__(16) uint4 Bsh4[1024];   // 16 KB, pre-swizzled [n][kk]

  const int tid = threadIdx.x, wid = tid>>6, lane = tid&63;
  const int b     = blockIdx.x & 7;          // XCD-affine batch
  const int chunk = blockIdx.x >> 3;
  const int ebase = b*E_ + chunk*256 + wid*64;
  const int eg  = ebase + lane;
  const int ein = eg & (E_-1);

  // B staging: linear copy of pre-swizzled bf16
  {
    const uint4* src = (const uint4*)((const char*)Btw + k*16384);
    #pragma unroll
    for(int i=0;i<4;i++) Bsh4[i*256+tid] = src[i*256+tid];
  }

  int   srcv = edge_index[b*2*E_ + ein];
  int   relv = rels[eg];
  float beta = sigm(bdot[relv] + qdot[b] + beta_b[0]);
  float gv   = (confm[eg]!=0) ? sigm((scores[eg]-beta)*10.0f) : 0.5f;

  int s_m[4], r_m[4];
  #pragma unroll
  for(int mt=0;mt<4;mt++){
    s_m[mt] = __shfl(srcv, mt*16 + (lane&15));
    r_m[mt] = __shfl(relv, mt*16 + (lane&15));
  }

  // p fragments kt=0 direct to registers
  bf16x8 af0[4];
  #pragma unroll
  for(int mt=0;mt<4;mt++){
    const float* hp = h + (size_t)(b*N_+s_m[mt])*64 + (lane>>4)*8;
    const float* rp = rel_table + (size_t)r_m[mt]*64 + (lane>>4)*8;
    af0[mt] = pk8(*(const float4*)hp, *(const float4*)(hp+4),
                  *(const float4*)rp, *(const float4*)(rp+4));
  }
  // conf fragments: direct global load, f32->bf16 in regs
  bf16x8 af2[4][2];
  {
    const float* cb = conf + (size_t)ebase*64;
    #pragma unroll
    for(int mt=0;mt<4;mt++)
      #pragma unroll
      for(int kt2=0;kt2<2;kt2++){
        const float* src = cb + (size_t)(mt*16 + (lane&15))*64 + kt2*32 + (lane>>4)*8;
        float4 u0 = *(const float4*)(src);
        float4 u1 = *(const float4*)(src+4);
        bf16x8 v;
        v[0]=(short)f2bf(u0.x); v[1]=(short)f2bf(u0.y); v[2]=(short)f2bf(u0.z); v[3]=(short)f2bf(u0.w);
        v[4]=(short)f2bf(u1.x); v[5]=(short)f2bf(u1.y); v[6]=(short)f2bf(u1.z); v[7]=(short)f2bf(u1.w);
        af2[mt][kt2] = v;
      }
  }
  __syncthreads();

  f32x4 acc[4][4];
  #pragma unroll
  for(int mt=0;mt<4;mt++)
    #pragma unroll
    for(int nt=0;nt<4;nt++) acc[mt][nt] = (f32x4){0.f,0.f,0.f,0.f};

  // kt=0: p @ W0[0:32]; prefetch kt=1 p-fragments
  bf16x8 af1[4];
  {
    bf16x8 bfr[4];
    int kbyte = (lane>>4)*16;
    #pragma unroll
    for(int nt=0;nt<4;nt++){
      int n = nt*16 + (lane&15);
      bfr[nt] = *(const bf16x8*)((const char*)Bsh4 + n*256 + (kbyte ^ ((n&7)<<4)));
    }
    #pragma unroll
    for(int mt=0;mt<4;mt++){
      const float* hp = h + (size_t)(b*N_+s_m[mt])*64 + 32 + (lane>>4)*8;
      const float* rp = rel_table + (size_t)r_m[mt]*64 + 32 + (lane>>4)*8;
      af1[mt] = pk8(*(const float4*)hp, *(const float4*)(hp+4),
                    *(const float4*)rp, *(const float4*)(rp+4));
    }
    #pragma unroll
    for(int mt=0;mt<4;mt++)
      #pragma unroll
      for(int nt=0;nt<4;nt++)
        acc[mt][nt] = __builtin_amdgcn_mfma_f32_16x16x32_bf16(af0[mt], bfr[nt], acc[mt][nt], 0,0,0);
  }
  // kt=1
  {
    bf16x8 bfr[4];
    int kbyte = 64 + (lane>>4)*16;
    #pragma unroll
    for(int nt=0;nt<4;nt++){
      int n = nt*16 + (lane&15);
      bfr[nt] = *(const bf16x8*)((const char*)Bsh4 + n*256 + (kbyte ^ ((n&7)<<4)));
    }
    #pragma unroll
    for(int mt=0;mt<4;mt++)
      #pragma unroll
      for(int nt=0;nt<4;nt++)
        acc[mt][nt] = __builtin_amdgcn_mfma_f32_16x16x32_bf16(af1[mt], bfr[nt], acc[mt][nt], 0,0,0);
  }
  // conf @ W4
  #pragma unroll
  for(int kt2=0;kt2<2;kt2++){
    bf16x8 bfr[4];
    int kbyte = 128 + kt2*64 + (lane>>4)*16;
    #pragma unroll
    for(int nt=0;nt<4;nt++){
      int n = nt*16 + (lane&15);
      bfr[nt] = *(const bf16x8*)((const char*)Bsh4 + n*256 + (kbyte ^ ((n&7)<<4)));
    }
    #pragma unroll
    for(int mt=0;mt<4;mt++)
      #pragma unroll
      for(int nt=0;nt<4;nt++)
        acc[mt][nt] = __builtin_amdgcn_mfma_f32_16x16x32_bf16(af2[mt][kt2], bfr[nt], acc[mt][nt], 0,0,0);
  }

  // epilogue: relu(D + statAdd + hW1')*gate -> bf16 row store (no atomics)
  #pragma unroll
  for(int mt=0;mt<4;mt++){
    #pragma unroll
    for(int jr=0;jr<4;jr++){
      int eloc  = mt*16 + (lane>>4)*4 + jr;
      int src_e = __shfl(srcv, eloc);
      int r_e   = __shfl(relv, eloc);
      float g_e = __shfl(gv,   eloc);
      const float* sa = statAdd + (size_t)(k*R_ + r_e)*64;
      const float* hw = hW1 + (size_t)(b*N_ + src_e)*64;
      unsigned short* wr = wmsg + (size_t)(ebase + eloc)*64;
      #pragma unroll
      for(int nt=0;nt<4;nt++){
        int j = nt*16 + (lane&15);
        float v = acc[mt][nt][jr] + sa[j] + hw[j];
        v = fmaxf(v, 0.f) * g_e;
        wr[j] = f2bf(v);
      }
    }
  }
}

// wide CSR gather (8 rows/instr) + h=LN(h+aggr@U+b); hW1' for next layer; ctx out
__global__ void k_update(const unsigned short* __restrict__ wmsg,
                         const int* __restrict__ off, const int* __restrict__ deg,
                         const unsigned short* __restrict__ eidlist,
                         const float* __restrict__ upd_w, const float* __restrict__ upd_b,
                         const float* __restrict__ ln_g, const float* __restrict__ ln_b,
                         const float* __restrict__ msg_w, const float* __restrict__ w2sum,
                         int k, float* __restrict__ h, float* __restrict__ hW1,
                         float* __restrict__ out){
  const int tid = threadIdx.x;
  const int wid = tid >> 6, lane = tid & 63;
  const int b = blockIdx.x & 7;              // XCD-affine: matches k_edge's wmsg writes
  const int n = (blockIdx.x >> 3)*4 + wid;
  const int j = lane;
  size_t idx = (size_t)(b*N_ + n)*64 + j;

  // ---- wide gather: lane = (row-slot l>>3, col-block (l&7)*8); 8 rows per VMEM instr ----
  int start = off[b*N_ + n];
  int dg    = deg[b*N_ + n];
  const unsigned short* wb = wmsg + (size_t)b*E_*64;
  const unsigned short* el = eidlist + b*E_ + start;
  const int rslot = lane >> 3;
  const int coff  = (lane & 7)*8;
  float as0=0.f,as1=0.f,as2=0.f,as3=0.f,as4=0.f,as5=0.f,as6=0.f,as7=0.f;
  for(int ib=0; ib<dg; ib+=8){
    int i = ib + rslot;
    if(i < dg){
      int e = el[i];
      uint4 q = *(const uint4*)(wb + (size_t)e*64 + coff);
      as0 += __uint_as_float(q.x << 16); as1 += __uint_as_float(q.x & 0xffff0000u);
      as2 += __uint_as_float(q.y << 16); as3 += __uint_as_float(q.y & 0xffff0000u);
      as4 += __uint_as_float(q.z << 16); as5 += __uint_as_float(q.z & 0xffff0000u);
      as6 += __uint_as_float(q.w << 16); as7 += __uint_as_float(q.w & 0xffff0000u);
    }
  }
  // reduce across the 8 row-slots (bits 3..5 of lane)
  #pragma unroll
  for(int o=8; o<64; o<<=1){
    as0 += __shfl_xor(as0,o,64); as1 += __shfl_xor(as1,o,64);
    as2 += __shfl_xor(as2,o,64); as3 += __shfl_xor(as3,o,64);
    as4 += __shfl_xor(as4,o,64); as5 += __shfl_xor(as5,o,64);
    as6 += __shfl_xor(as6,o,64); as7 += __shfl_xor(as7,o,64);
  }
  // lane l now holds colsums for cols (l&7)*8 .. +8 ; a_i = shfl(as[i&7], i>>3)
  #define A_OF(i) __shfl( ((i)&7)==0?as0:((i)&7)==1?as1:((i)&7)==2?as2:((i)&7)==3?as3: \
                          ((i)&7)==4?as4:((i)&7)==5?as5:((i)&7)==6?as6:as7, (i)>>3, 64)

  const float* U = upd_w + k*D_*D_;
  float c0 = h[idx] + upd_b[k*D_+j], c1 = 0.f, c2 = 0.f, c3 = 0.f;
  #pragma unroll
  for(int i=0;i<16;i++){
    c0 += A_OF(i)    * U[(i)*D_+j];
    c1 += A_OF(i+16) * U[(i+16)*D_+j];
    c2 += A_OF(i+32) * U[(i+32)*D_+j];
    c3 += A_OF(i+48) * U[(i+48)*D_+j];
  }
  float acc = (c0+c1)+(c2+c3);
  float s = acc, sq = acc*acc;
  #pragma unroll
  for(int o=32; o; o>>=1){
    s  += __shfl_xor(s,  o, 64);
    sq += __shfl_xor(sq, o, 64);
  }
  float mean = s * (1.0f/64.0f);
  float var  = sq * (1.0f/64.0f) - mean*mean;
  float y = (acc - mean)*rsqrtf(var + EPS_)*ln_g[j] + ln_b[j];
  h[idx] = y;
  if(n==0) out[(b*L_+k)*D_+j] = y;
  if(k < L_-1){
    const float* W1 = msg_w + (k+1)*5*D_*D_ + D_*D_;
    float w0 = 0.f, w1 = 0.f, w2 = 0.f, w3 = 0.f;
    #pragma unroll
    for(int i=0;i<16;i++){
      w0 += __shfl(y, i,    64) * W1[(i)*D_+j];
      w1 += __shfl(y, i+16, 64) * W1[(i+16)*D_+j];
      w2 += __shfl(y, i+32, 64) * W1[(i+32)*D_+j];
      w3 += __shfl(y, i+48, 64) * W1[(i+48)*D_+j];
    }
    hW1[idx] = (w0+w1)+(w2+w3) + ((n==0) ? w2sum[(k+1)*D_+j] : 0.0f);
  }
}

extern "C" void kernel_launch(void* const* d_in, const int* in_sizes, int n_in,
                              void* d_out, int out_size, void* d_ws, size_t ws_size,
                              hipStream_t stream) {
  const int*   edge_index = (const int*)d_in[0];
  const int*   rels       = (const int*)d_in[1];
  const float* scores     = (const float*)d_in[2];
  const int*   confm      = (const int*)d_in[3];
  const float* r_query    = (const float*)d_in[6];
  const float* rel_table  = (const float*)d_in[7];
  const float* conf       = (const float*)d_in[8];
  const float* beta_w     = (const float*)d_in[9];
  const float* beta_b     = (const float*)d_in[10];
  const float* msg_w      = (const float*)d_in[11];
  const float* msg_b      = (const float*)d_in[12];
  const float* upd_w      = (const float*)d_in[13];
  const float* upd_b      = (const float*)d_in[14];
  const float* ln_g       = (const float*)d_in[15];
  const float* ln_b       = (const float*)d_in[16];
  float* out = (float*)d_out;

  float* ws      = (float*)d_ws;
  float* h       = ws;                          // 2,097,152 f
  float* hW1     = h + B_*N_*D_;                // 2,097,152 f
  float* statAdd = hW1 + B_*N_*D_;              // 96,000 f
  float* w2sum   = statAdd + L_*R_*D_;          // 192 f
  float* w1sum0  = w2sum + L_*D_;               // 64 f
  float* bdot    = w1sum0 + D_;                 // 512 f
  float* qdot    = bdot + 512;                  // 64 f
  unsigned short* Btw = (unsigned short*)(qdot + 64);      // 24,576 u16
  int* deg    = (int*)(((float*)Btw) + 12288);  // 32,768 i32
  int* off    = deg + B_*N_;                    // 32,768 i32
  int* cursor = off + B_*N_;                    // 32,768 i32
  unsigned short* eidlist = (unsigned short*)(cursor + B_*N_);   // 262,144 u16
  unsigned short* wmsg    = eidlist + B_*E_;    // 16,777,216 u16 (32 MB)

  k_prep<<<L_*R_+4+R_+B_, 64, 0, stream>>>(rel_table, r_query, beta_w, msg_w, msg_b,
                                           statAdd, w2sum, w1sum0, bdot, qdot);
  k_prepw<<<(L_*8192+255)/256, 256, 0, stream>>>(msg_w, Btw);
  k_init<<<(B_*N_*D_)/256, 256, 0, stream>>>(h, hW1, w1sum0, w2sum);
  hipMemsetAsync(deg, 0, (size_t)B_*N_*sizeof(int), stream);
  k_hist<<<(B_*E_)/256, 256, 0, stream>>>(edge_index, deg);
  k_scan<<<B_, 1024, 0, stream>>>(deg, off, cursor);
  k_fill<<<(B_*E_)/256, 256, 0, stream>>>(edge_index, cursor, eidlist);

  for(int k=0;k<L_;k++){
    k_edge<<<(B_*E_)/256, 256, 0, stream>>>(edge_index, rels, scores, confm, bdot, qdot,
                                            beta_b, h, hW1, rel_table, conf, Btw,
                                            statAdd, k, wmsg);
    k_update<<<(B_*N_)/4, 256, 0, stream>>>(wmsg, off, deg, eidlist, upd_w, upd_b,
                                            ln_g, ln_b, msg_w, w2sum, k, h, hW1, out);
  }
}

// Round 9
// 230.184 us; speedup vs baseline: 2.0681x; 1.5160x over previous
//
#include <hip/hip_runtime.h>

#define B_ 8
#define E_ 32768
#define N_ 4096
#define D_ 64
#define R_ 500
#define L_ 3
#define EPS_ 1e-5f

typedef short bf16x8 __attribute__((ext_vector_type(8)));
typedef float f32x4 __attribute__((ext_vector_type(4)));

__device__ __forceinline__ float sigm(float x){ return 1.0f/(1.0f+__expf(-x)); }
__device__ __forceinline__ unsigned short f2bf(float x){
  unsigned u = __float_as_uint(x);
  u += 0x7fffu + ((u>>16)&1u);
  return (unsigned short)(u>>16);
}
__device__ __forceinline__ bf16x8 pk8(float4 a0, float4 a1, float4 b0, float4 b1){
  bf16x8 v;
  v[0]=(short)f2bf(a0.x*b0.x); v[1]=(short)f2bf(a0.y*b0.y);
  v[2]=(short)f2bf(a0.z*b0.z); v[3]=(short)f2bf(a0.w*b0.w);
  v[4]=(short)f2bf(a1.x*b1.x); v[5]=(short)f2bf(a1.y*b1.y);
  v[6]=(short)f2bf(a1.z*b1.z); v[7]=(short)f2bf(a1.w*b1.w);
  return v;
}

// fused prep: [0,1500): statAdd; [1500,1503): w2sum; 1503: w1sum0; [1504,..): betadot
__global__ void k_prep(const float* __restrict__ rel_table, const float* __restrict__ r_query,
                       const float* __restrict__ beta_w, const float* __restrict__ msg_w,
                       const float* __restrict__ msg_b,
                       float* __restrict__ statAdd, float* __restrict__ w2sum,
                       float* __restrict__ w1sum0, float* __restrict__ bdot,
                       float* __restrict__ qdot){
  int blk = blockIdx.x, j = threadIdx.x;   // 64 threads
  if(blk < L_*R_){
    int k = blk/R_, r = blk%R_;
    const float* W3 = msg_w + k*5*D_*D_ + 3*D_*D_;
    const float* rt = rel_table + r*D_;
    float s = msg_b[k*D_+j];
    #pragma unroll
    for(int i=0;i<D_;i++) s += rt[i]*W3[i*D_+j];
    statAdd[(k*R_+r)*D_+j] = s;
  } else if(blk < L_*R_+3){
    int k = blk - L_*R_;
    const float* W2 = msg_w + k*5*D_*D_ + 2*D_*D_;
    float s = 0.f;
    #pragma unroll
    for(int i=0;i<D_;i++) s += W2[i*D_+j];
    w2sum[k*D_+j] = s;
  } else if(blk == L_*R_+3){
    const float* W1 = msg_w + 1*D_*D_;
    float s = 0.f;
    #pragma unroll
    for(int i=0;i<D_;i++) s += W1[i*D_+j];
    w1sum0[j] = s;
  } else {
    int item = blk - (L_*R_+4);
    if(item >= R_+B_) return;
    float x = (item < R_ ? rel_table[item*D_+j] : r_query[(item-R_)*D_+j]) * beta_w[j];
    #pragma unroll
    for(int off=32; off; off>>=1) x += __shfl_xor(x, off, 64);
    if(j==0){ if(item < R_) bdot[item] = x; else qdot[item-R_] = x; }
  }
}

// W0|W4 -> transposed, pre-swizzled bf16 (for k_edge B operand)
__global__ void k_prepw(const float* __restrict__ msg_w, unsigned short* __restrict__ Btw){
  int t = blockIdx.x*256 + threadIdx.x;      // L_*8192
  if(t >= L_*8192) return;
  int k = t >> 13, rem = t & 8191;
  int n = rem >> 7, kk = rem & 127;
  const float* W0 = msg_w + k*5*D_*D_;
  float v = (kk<64) ? W0[kk*64+n] : W0[4*D_*D_ + (kk-64)*64+n];
  *(unsigned short*)((char*)Btw + k*16384 + n*256 + ((kk*2) ^ ((n&7)<<4))) = f2bf(v);
}

// U_k | W1_{k+1} -> transposed, pre-swizzled bf16 (for k_update B operands)
// per layer: [0,8KB) = U_k, [8KB,16KB) = W1_{k+1} (zeros for k=L-1). 64x64 each, 128B rows.
__global__ void k_prepu(const float* __restrict__ upd_w, const float* __restrict__ msg_w,
                        unsigned short* __restrict__ UWtw){
  int t = blockIdx.x*256 + threadIdx.x;      // L_*2*4096 = 24576
  if(t >= L_*8192) return;
  int k = t >> 13, rem = t & 8191;
  int sel = rem >> 12, idx = rem & 4095;
  int n = idx >> 6, kk = idx & 63;
  float v;
  if(sel==0) v = upd_w[k*D_*D_ + kk*64 + n];
  else       v = (k < L_-1) ? msg_w[(k+1)*5*D_*D_ + D_*D_ + kk*64 + n] : 0.f;
  *(unsigned short*)((char*)UWtw + k*16384 + sel*8192 + n*128 + ((kk*2) ^ ((n&7)<<4))) = f2bf(v);
}

// h init; hW1' (layer0, w2sum folded) init
__global__ void k_init(float* __restrict__ h, float* __restrict__ hW1,
                       const float* __restrict__ w1sum0, const float* __restrict__ w2sum){
  int idx = blockIdx.x*256 + threadIdx.x;
  int n = (idx / D_) & (N_-1);
  int j = idx & (D_-1);
  bool z = (n==0);
  h[idx]   = z ? 1.0f : 0.0f;
  hW1[idx] = z ? (w1sum0[j] + w2sum[j]) : 0.0f;
}

// CSR build: histogram of tgt
__global__ void k_hist(const int* __restrict__ edge_index, int* __restrict__ deg){
  int idx = blockIdx.x*256 + threadIdx.x;    // B*E
  int b = idx >> 15, e = idx & (E_-1);
  int tgt = edge_index[b*2*E_ + E_ + e];
  atomicAdd(&deg[b*N_ + tgt], 1);
}

// per-batch exclusive scan of deg -> off, cursor
__global__ void k_scan(const int* __restrict__ deg, int* __restrict__ off,
                       int* __restrict__ cursor){
  int b = blockIdx.x, t = threadIdx.x;
  int base = b*N_ + t*4;
  int v0 = deg[base], v1 = deg[base+1], v2 = deg[base+2], v3 = deg[base+3];
  int s = v0+v1+v2+v3;
  int lane = t & 63, w = t >> 6;             // 16 waves
  int x = s;
  #pragma unroll
  for(int d=1; d<64; d<<=1){
    int y = __shfl_up(x, d, 64);
    if(lane >= d) x += y;
  }
  int wave_excl = x - s;
  __shared__ int wsum[16];
  if(lane==63) wsum[w] = x;
  __syncthreads();
  int wbase = 0;
  for(int i=0;i<w;i++) wbase += wsum[i];
  int excl = wbase + wave_excl;
  off[base]   = excl;           cursor[base]   = excl;
  off[base+1] = excl+v0;        cursor[base+1] = excl+v0;
  off[base+2] = excl+v0+v1;     cursor[base+2] = excl+v0+v1;
  off[base+3] = excl+v0+v1+v2;  cursor[base+3] = excl+v0+v1+v2;
}

__global__ void k_fill(const int* __restrict__ edge_index, int* __restrict__ cursor,
                       unsigned short* __restrict__ eidlist){
  int idx = blockIdx.x*256 + threadIdx.x;    // B*E
  int b = idx >> 15, e = idx & (E_-1);
  int tgt = edge_index[b*2*E_ + E_ + e];
  int pos = atomicAdd(&cursor[b*N_ + tgt], 1);
  eidlist[b*E_ + pos] = (unsigned short)e;
}

// MFMA edge kernel -> dense bf16 message rows (no atomics)  [unchanged from R8]
__global__ void __launch_bounds__(256,3) k_edge(
    const int* __restrict__ edge_index, const int* __restrict__ rels,
    const float* __restrict__ scores, const int* __restrict__ confm,
    const float* __restrict__ bdot, const float* __restrict__ qdot,
    const float* __restrict__ beta_b,
    const float* __restrict__ h, const float* __restrict__ hW1,
    const float* __restrict__ rel_table, const float* __restrict__ conf,
    const unsigned short* __restrict__ Btw, const float* __restrict__ statAdd,
    int k, unsigned short* __restrict__ wmsg){
  __shared__ __align__(16) uint4 Bsh4[1024];   // 16 KB, pre-swizzled [n][kk]

  const int tid = threadIdx.x, wid = tid>>6, lane = tid&63;
  const int b     = blockIdx.x & 7;
  const int chunk = blockIdx.x >> 3;
  const int ebase = b*E_ + chunk*256 + wid*64;
  const int eg  = ebase + lane;
  const int ein = eg & (E_-1);

  {
    const uint4* src = (const uint4*)((const char*)Btw + k*16384);
    #pragma unroll
    for(int i=0;i<4;i++) Bsh4[i*256+tid] = src[i*256+tid];
  }

  int   srcv = edge_index[b*2*E_ + ein];
  int   relv = rels[eg];
  float beta = sigm(bdot[relv] + qdot[b] + beta_b[0]);
  float gv   = (confm[eg]!=0) ? sigm((scores[eg]-beta)*10.0f) : 0.5f;

  int s_m[4], r_m[4];
  #pragma unroll
  for(int mt=0;mt<4;mt++){
    s_m[mt] = __shfl(srcv, mt*16 + (lane&15));
    r_m[mt] = __shfl(relv, mt*16 + (lane&15));
  }

  bf16x8 af0[4];
  #pragma unroll
  for(int mt=0;mt<4;mt++){
    const float* hp = h + (size_t)(b*N_+s_m[mt])*64 + (lane>>4)*8;
    const float* rp = rel_table + (size_t)r_m[mt]*64 + (lane>>4)*8;
    af0[mt] = pk8(*(const float4*)hp, *(const float4*)(hp+4),
                  *(const float4*)rp, *(const float4*)(rp+4));
  }
  bf16x8 af2[4][2];
  {
    const float* cb = conf + (size_t)ebase*64;
    #pragma unroll
    for(int mt=0;mt<4;mt++)
      #pragma unroll
      for(int kt2=0;kt2<2;kt2++){
        const float* src = cb + (size_t)(mt*16 + (lane&15))*64 + kt2*32 + (lane>>4)*8;
        float4 u0 = *(const float4*)(src);
        float4 u1 = *(const float4*)(src+4);
        bf16x8 v;
        v[0]=(short)f2bf(u0.x); v[1]=(short)f2bf(u0.y); v[2]=(short)f2bf(u0.z); v[3]=(short)f2bf(u0.w);
        v[4]=(short)f2bf(u1.x); v[5]=(short)f2bf(u1.y); v[6]=(short)f2bf(u1.z); v[7]=(short)f2bf(u1.w);
        af2[mt][kt2] = v;
      }
  }
  __syncthreads();

  f32x4 acc[4][4];
  #pragma unroll
  for(int mt=0;mt<4;mt++)
    #pragma unroll
    for(int nt=0;nt<4;nt++) acc[mt][nt] = (f32x4){0.f,0.f,0.f,0.f};

  bf16x8 af1[4];
  {
    bf16x8 bfr[4];
    int kbyte = (lane>>4)*16;
    #pragma unroll
    for(int nt=0;nt<4;nt++){
      int n = nt*16 + (lane&15);
      bfr[nt] = *(const bf16x8*)((const char*)Bsh4 + n*256 + (kbyte ^ ((n&7)<<4)));
    }
    #pragma unroll
    for(int mt=0;mt<4;mt++){
      const float* hp = h + (size_t)(b*N_+s_m[mt])*64 + 32 + (lane>>4)*8;
      const float* rp = rel_table + (size_t)r_m[mt]*64 + 32 + (lane>>4)*8;
      af1[mt] = pk8(*(const float4*)hp, *(const float4*)(hp+4),
                    *(const float4*)rp, *(const float4*)(rp+4));
    }
    #pragma unroll
    for(int mt=0;mt<4;mt++)
      #pragma unroll
      for(int nt=0;nt<4;nt++)
        acc[mt][nt] = __builtin_amdgcn_mfma_f32_16x16x32_bf16(af0[mt], bfr[nt], acc[mt][nt], 0,0,0);
  }
  {
    bf16x8 bfr[4];
    int kbyte = 64 + (lane>>4)*16;
    #pragma unroll
    for(int nt=0;nt<4;nt++){
      int n = nt*16 + (lane&15);
      bfr[nt] = *(const bf16x8*)((const char*)Bsh4 + n*256 + (kbyte ^ ((n&7)<<4)));
    }
    #pragma unroll
    for(int mt=0;mt<4;mt++)
      #pragma unroll
      for(int nt=0;nt<4;nt++)
        acc[mt][nt] = __builtin_amdgcn_mfma_f32_16x16x32_bf16(af1[mt], bfr[nt], acc[mt][nt], 0,0,0);
  }
  #pragma unroll
  for(int kt2=0;kt2<2;kt2++){
    bf16x8 bfr[4];
    int kbyte = 128 + kt2*64 + (lane>>4)*16;
    #pragma unroll
    for(int nt=0;nt<4;nt++){
      int n = nt*16 + (lane&15);
      bfr[nt] = *(const bf16x8*)((const char*)Bsh4 + n*256 + (kbyte ^ ((n&7)<<4)));
    }
    #pragma unroll
    for(int mt=0;mt<4;mt++)
      #pragma unroll
      for(int nt=0;nt<4;nt++)
        acc[mt][nt] = __builtin_amdgcn_mfma_f32_16x16x32_bf16(af2[mt][kt2], bfr[nt], acc[mt][nt], 0,0,0);
  }

  #pragma unroll
  for(int mt=0;mt<4;mt++){
    #pragma unroll
    for(int jr=0;jr<4;jr++){
      int eloc  = mt*16 + (lane>>4)*4 + jr;
      int src_e = __shfl(srcv, eloc);
      int r_e   = __shfl(relv, eloc);
      float g_e = __shfl(gv,   eloc);
      const float* sa = statAdd + (size_t)(k*R_ + r_e)*64;
      const float* hw = hW1 + (size_t)(b*N_ + src_e)*64;
      unsigned short* wr = wmsg + (size_t)(ebase + eloc)*64;
      #pragma unroll
      for(int nt=0;nt<4;nt++){
        int j = nt*16 + (lane&15);
        float v = acc[mt][nt][jr] + sa[j] + hw[j];
        v = fmaxf(v, 0.f) * g_e;
        wr[j] = f2bf(v);
      }
    }
  }
}

// MFMA node update: block = 64 nodes (4 waves x 16). Gather aggr into A-fragments,
// aggr@U via MFMA, +h +bias, LN in C-layout, y@W1_{k+1} via swizzled-LDS transpose + MFMA.
__global__ void __launch_bounds__(256,2) k_update(
    const unsigned short* __restrict__ wmsg,
    const int* __restrict__ off, const int* __restrict__ deg,
    const unsigned short* __restrict__ eidlist,
    const unsigned short* __restrict__ UWtw,
    const float* __restrict__ upd_b, const float* __restrict__ ln_g,
    const float* __restrict__ ln_b, const float* __restrict__ w2sum,
    int k, float* __restrict__ h, float* __restrict__ hW1,
    float* __restrict__ out){
  __shared__ __align__(16) uint4 Ush4[512];                 // 8 KB  U_k (pre-swizzled)
  __shared__ __align__(16) uint4 Wsh4[512];                 // 8 KB  W1_{k+1}
  __shared__ __align__(16) unsigned short Ysh[4*1024];      // 8 KB  per-wave y (swizzled)

  const int tid = threadIdx.x, wid = tid>>6, lane = tid&63;
  const int b  = blockIdx.x & 7;                 // XCD-affine: matches k_edge wmsg writes
  const int nb = (blockIdx.x >> 3) * 64;

  // stage U + W1 (pre-swizzled bf16, linear copy)
  {
    const uint4* src = (const uint4*)((const char*)UWtw + (size_t)k*16384);
    Ush4[tid]     = src[tid];
    Ush4[256+tid] = src[256+tid];
    Wsh4[tid]     = src[512+tid];
    Wsh4[256+tid] = src[768+tid];
  }

  // ---- gather aggr directly into MFMA A-fragment layout ----
  // lane: node nd = nb + wid*16 + (lane&15); k-chunk = (lane>>4)*8 (x2 kt halves)
  const int nd    = nb + wid*16 + (lane&15);
  const int cbase = b*N_ + nd;
  int o0 = off[cbase], dg = deg[cbase];
  int mdg = dg;
  #pragma unroll
  for(int o=1;o<16;o<<=1) mdg = max(mdg, __shfl_xor(mdg, o, 64));

  const unsigned short* el = eidlist + b*E_ + o0;
  const unsigned short* wb = wmsg + (size_t)b*E_*64;
  const int cb = (lane>>4)*8;                    // bf16 col base within a 32-col half

  float a0[8], a1[8];
  #pragma unroll
  for(int u=0;u<8;u++){ a0[u]=0.f; a1[u]=0.f; }

  for(int c=0; c<mdg; c+=8){
    int e_[8];
    #pragma unroll
    for(int u=0;u<8;u++) e_[u] = el[c+u];        // may over-read; use guarded below
    #pragma unroll
    for(int u=0;u<8;u++){
      if(c+u < dg){
        const unsigned short* rp = wb + (size_t)e_[u]*64 + cb;
        uint4 q0 = *(const uint4*)(rp);
        uint4 q1 = *(const uint4*)(rp+32);
        a0[0]+=__uint_as_float(q0.x<<16); a0[1]+=__uint_as_float(q0.x&0xffff0000u);
        a0[2]+=__uint_as_float(q0.y<<16); a0[3]+=__uint_as_float(q0.y&0xffff0000u);
        a0[4]+=__uint_as_float(q0.z<<16); a0[5]+=__uint_as_float(q0.z&0xffff0000u);
        a0[6]+=__uint_as_float(q0.w<<16); a0[7]+=__uint_as_float(q0.w&0xffff0000u);
        a1[0]+=__uint_as_float(q1.x<<16); a1[1]+=__uint_as_float(q1.x&0xffff0000u);
        a1[2]+=__uint_as_float(q1.y<<16); a1[3]+=__uint_as_float(q1.y&0xffff0000u);
        a1[4]+=__uint_as_float(q1.z<<16); a1[5]+=__uint_as_float(q1.z&0xffff0000u);
        a1[6]+=__uint_as_float(q1.w<<16); a1[7]+=__uint_as_float(q1.w&0xffff0000u);
      }
    }
  }
  bf16x8 afU[2];
  #pragma unroll
  for(int u=0;u<8;u++){ afU[0][u]=(short)f2bf(a0[u]); afU[1][u]=(short)f2bf(a1[u]); }
  __syncthreads();                               // U/W staging visible

  // ---- aggr @ U ----
  f32x4 acc[4];
  #pragma unroll
  for(int nt=0;nt<4;nt++) acc[nt] = (f32x4){0.f,0.f,0.f,0.f};
  #pragma unroll
  for(int kt=0;kt<2;kt++){
    #pragma unroll
    for(int nt=0;nt<4;nt++){
      int n = nt*16 + (lane&15);
      bf16x8 bfr = *(const bf16x8*)((const char*)Ush4 + n*128 + ((kt*64 + (lane>>4)*16) ^ ((n&7)<<4)));
      acc[nt] = __builtin_amdgcn_mfma_f32_16x16x32_bf16(afU[kt], bfr, acc[nt], 0,0,0);
    }
  }

  // ---- + h + bias; LN over j (C-layout: row=(lane>>4)*4+jr, col=nt*16+(lane&15)) ----
  float val[4][4];                               // [jr][nt]
  float sum_[4], sq_[4];
  #pragma unroll
  for(int jr=0;jr<4;jr++){ sum_[jr]=0.f; sq_[jr]=0.f; }
  #pragma unroll
  for(int jr=0;jr<4;jr++){
    int nd2 = nb + wid*16 + (lane>>4)*4 + jr;
    #pragma unroll
    for(int nt=0;nt<4;nt++){
      int j = nt*16 + (lane&15);
      float v = acc[nt][jr] + h[(size_t)(b*N_+nd2)*64 + j] + upd_b[k*64 + j];
      val[jr][nt] = v;
      sum_[jr] += v; sq_[jr] += v*v;
    }
  }
  #pragma unroll
  for(int o=1;o<16;o<<=1){
    #pragma unroll
    for(int jr=0;jr<4;jr++){
      sum_[jr] += __shfl_xor(sum_[jr], o, 64);
      sq_[jr]  += __shfl_xor(sq_[jr],  o, 64);
    }
  }
  unsigned short* ysw = Ysh + wid*1024;
  #pragma unroll
  for(int jr=0;jr<4;jr++){
    int rr  = (lane>>4)*4 + jr;
    int nd2 = nb + wid*16 + rr;
    float mean = sum_[jr]*(1.0f/64.0f);
    float var  = sq_[jr]*(1.0f/64.0f) - mean*mean;
    float inv  = rsqrtf(var + EPS_);
    #pragma unroll
    for(int nt=0;nt<4;nt++){
      int j = nt*16 + (lane&15);
      float y = (val[jr][nt] - mean)*inv*ln_g[j] + ln_b[j];
      h[(size_t)(b*N_+nd2)*64 + j] = y;
      if(nd2==0) out[(b*L_+k)*64 + j] = y;
      if(k < L_-1)
        *(unsigned short*)((char*)ysw + rr*128 + ((j*2) ^ ((rr&7)<<4))) = f2bf(y);
    }
  }

  // ---- y @ W1_{k+1} (A from wave-private swizzled LDS; DS ops wave-ordered, no barrier) ----
  if(k < L_-1){
    f32x4 accw[4];
    #pragma unroll
    for(int nt=0;nt<4;nt++) accw[nt] = (f32x4){0.f,0.f,0.f,0.f};
    #pragma unroll
    for(int kt=0;kt<2;kt++){
      int row = lane&15;
      bf16x8 af = *(const bf16x8*)((const char*)ysw + row*128 + ((kt*64 + (lane>>4)*16) ^ ((row&7)<<4)));
      #pragma unroll
      for(int nt=0;nt<4;nt++){
        int n = nt*16 + (lane&15);
        bf16x8 bfr = *(const bf16x8*)((const char*)Wsh4 + n*128 + ((kt*64 + (lane>>4)*16) ^ ((n&7)<<4)));
        accw[nt] = __builtin_amdgcn_mfma_f32_16x16x32_bf16(af, bfr, accw[nt], 0,0,0);
      }
    }
    #pragma unroll
    for(int jr=0;jr<4;jr++){
      int nd2 = nb + wid*16 + (lane>>4)*4 + jr;
      #pragma unroll
      for(int nt=0;nt<4;nt++){
        int j = nt*16 + (lane&15);
        float v = accw[nt][jr] + ((nd2==0) ? w2sum[(k+1)*64 + j] : 0.0f);
        hW1[(size_t)(b*N_+nd2)*64 + j] = v;
      }
    }
  }
}

extern "C" void kernel_launch(void* const* d_in, const int* in_sizes, int n_in,
                              void* d_out, int out_size, void* d_ws, size_t ws_size,
                              hipStream_t stream) {
  const int*   edge_index = (const int*)d_in[0];
  const int*   rels       = (const int*)d_in[1];
  const float* scores     = (const float*)d_in[2];
  const int*   confm      = (const int*)d_in[3];
  const float* r_query    = (const float*)d_in[6];
  const float* rel_table  = (const float*)d_in[7];
  const float* conf       = (const float*)d_in[8];
  const float* beta_w     = (const float*)d_in[9];
  const float* beta_b     = (const float*)d_in[10];
  const float* msg_w      = (const float*)d_in[11];
  const float* msg_b      = (const float*)d_in[12];
  const float* upd_w      = (const float*)d_in[13];
  const float* upd_b      = (const float*)d_in[14];
  const float* ln_g       = (const float*)d_in[15];
  const float* ln_b       = (const float*)d_in[16];
  float* out = (float*)d_out;

  float* ws      = (float*)d_ws;
  float* h       = ws;                          // 2,097,152 f
  float* hW1     = h + B_*N_*D_;                // 2,097,152 f
  float* statAdd = hW1 + B_*N_*D_;              // 96,000 f
  float* w2sum   = statAdd + L_*R_*D_;          // 192 f
  float* w1sum0  = w2sum + L_*D_;               // 64 f
  float* bdot    = w1sum0 + D_;                 // 512 f
  float* qdot    = bdot + 512;                  // 64 f
  unsigned short* Btw  = (unsigned short*)(qdot + 64);     // 24,576 u16
  unsigned short* UWtw = Btw + L_*8192;                    // 24,576 u16
  int* deg    = (int*)(UWtw + L_*8192);
  int* off    = deg + B_*N_;
  int* cursor = off + B_*N_;
  unsigned short* eidlist = (unsigned short*)(cursor + B_*N_);   // 262,144 u16
  unsigned short* wmsg    = eidlist + B_*E_;    // 16,777,216 u16 (32 MB)

  k_prep<<<L_*R_+4+R_+B_, 64, 0, stream>>>(rel_table, r_query, beta_w, msg_w, msg_b,
                                           statAdd, w2sum, w1sum0, bdot, qdot);
  k_prepw<<<(L_*8192+255)/256, 256, 0, stream>>>(msg_w, Btw);
  k_prepu<<<(L_*8192+255)/256, 256, 0, stream>>>(upd_w, msg_w, UWtw);
  k_init<<<(B_*N_*D_)/256, 256, 0, stream>>>(h, hW1, w1sum0, w2sum);
  hipMemsetAsync(deg, 0, (size_t)B_*N_*sizeof(int), stream);
  k_hist<<<(B_*E_)/256, 256, 0, stream>>>(edge_index, deg);
  k_scan<<<B_, 1024, 0, stream>>>(deg, off, cursor);
  k_fill<<<(B_*E_)/256, 256, 0, stream>>>(edge_index, cursor, eidlist);

  for(int k=0;k<L_;k++){
    k_edge<<<(B_*E_)/256, 256, 0, stream>>>(edge_index, rels, scores, confm, bdot, qdot,
                                            beta_b, h, hW1, rel_table, conf, Btw,
                                            statAdd, k, wmsg);
    k_update<<<(B_*N_)/64, 256, 0, stream>>>(wmsg, off, deg, eidlist, UWtw, upd_b,
                                             ln_g, ln_b, w2sum, k, h, hW1, out);
  }
}